// Round 2
// baseline (505.581 us; speedup 1.0000x reference)
//
#include <hip/hip_runtime.h>
#include <cstdint>
#include <cstddef>

// Problem constants (B=8, S=2048, D=1024)
#define BATCH 8
#define SEQ   2048
#define DM    1024

typedef _Float16 half8 __attribute__((ext_vector_type(8)));
typedef float floatx4 __attribute__((ext_vector_type(4)));

#define GLOBAL_AS __attribute__((address_space(1)))
#define LDS_AS    __attribute__((address_space(3)))

// Async global->LDS, 16B per lane. LDS dest = wave-uniform base + lane*16.
__device__ __forceinline__ void gl_lds16(const _Float16* g, _Float16* l) {
    __builtin_amdgcn_global_load_lds((const GLOBAL_AS void*)g, (LDS_AS void*)l, 16, 0, 0);
}

// ---------------------------------------------------------------------------
// gemm_bt mainloop: C[m][n] = sum_k A[m][k] * B[n][k]
// Tile BM=BN=128, BK=32. Block = 256 threads = 4 waves in 2x2.
// ---------------------------------------------------------------------------
__device__ __forceinline__ void gemm_bt_tile(
    const _Float16* __restrict__ A, const _Float16* __restrict__ B,
    int lda, int ldb, int kmax,
    _Float16* As, _Float16* Bs, floatx4 (&acc)[4][4])
{
    const int t = threadIdx.x;
    const int wave = t >> 6, lane = t & 63;
    const int l15 = lane & 15, kq = lane >> 4;
    const int wm = (wave >> 1) * 64, wn = (wave & 1) * 64;
    const int sr = t >> 2;          // staging row 0..63
    const int sc = (t & 3) * 8;     // staging col (elements)
    _Float16* AsW = As + wave * 512;  // wave-uniform LDS base
    _Float16* BsW = Bs + wave * 512;

    for (int k0 = 0; k0 < kmax; k0 += 32) {
        __syncthreads();
        gl_lds16(A + (size_t)sr * lda + k0 + sc,        AsW);
        gl_lds16(A + (size_t)(sr + 64) * lda + k0 + sc, AsW + 2048);
        gl_lds16(B + (size_t)sr * ldb + k0 + sc,        BsW);
        gl_lds16(B + (size_t)(sr + 64) * ldb + k0 + sc, BsW + 2048);
        __syncthreads();

        half8 af[4], bfr[4];
        #pragma unroll
        for (int i = 0; i < 4; i++)
            af[i] = *(const half8*)&As[(wm + i * 16 + l15) * 32 + kq * 8];
        #pragma unroll
        for (int j = 0; j < 4; j++)
            bfr[j] = *(const half8*)&Bs[(wn + j * 16 + l15) * 32 + kq * 8];
        #pragma unroll
        for (int i = 0; i < 4; i++)
            #pragma unroll
            for (int j = 0; j < 4; j++)
                acc[i][j] = __builtin_amdgcn_mfma_f32_16x16x32_f16(af[i], bfr[j], acc[i][j], 0, 0, 0);
    }
}

// ---------------------------------------------------------------------------
// Kernel 1: fp32 -> fp16 (src -> Xh (lives in d_out), Wk/Wv/Wq -> Wh)
// ---------------------------------------------------------------------------
__global__ __launch_bounds__(256) void convert_inputs(
    const float* __restrict__ src,
    const float* __restrict__ Wk, const float* __restrict__ Wv, const float* __restrict__ Wq,
    _Float16* __restrict__ Xh, _Float16* __restrict__ Wh)
{
    const int64_t gid = (int64_t)blockIdx.x * 256 + threadIdx.x;
    const int64_t gs  = (int64_t)gridDim.x * 256;
    const int64_t nX = (int64_t)BATCH * SEQ * DM;
    const int64_t nW = (int64_t)DM * DM;
    for (int64_t i = gid; i < nX; i += gs) Xh[i] = (_Float16)src[i];
    for (int64_t i = gid; i < nW; i += gs) {
        Wh[i]          = (_Float16)Wk[i];
        Wh[nW + i]     = (_Float16)Wv[i];
        Wh[2 * nW + i] = (_Float16)Wq[i];
    }
}

// ---------------------------------------------------------------------------
// Kernel 2: QKV projection.
//   z=0: K[s][d]  = X·Wk^T + bk          (by = s-tile 0..127, bx = d-tile 0..7)
//   z=1: Vt[d][s] = Wv·X^T + bv[row]     (by = (b,s)-tile,    bx = d-tile)
//   z=2: Q[s][d]  = X·Wq^T + bq
// ---------------------------------------------------------------------------
__global__ __launch_bounds__(256) void qkv_gemm(
    const _Float16* __restrict__ Xh, const _Float16* __restrict__ Wh,
    const float* __restrict__ bk, const float* __restrict__ bv, const float* __restrict__ bq,
    _Float16* __restrict__ Kh, _Float16* __restrict__ Vt, _Float16* __restrict__ Qh)
{
    __shared__ __align__(16) _Float16 As[128 * 32];
    __shared__ __align__(16) _Float16 Bs[128 * 32];
    const int bx = blockIdx.x, by = blockIdx.y, z = blockIdx.z;
    const _Float16 *A, *B;
    if (z == 1) {
        A = Wh + (size_t)DM * DM + (size_t)bx * 128 * DM;   // Wv rows (d)
        B = Xh + (size_t)by * 128 * DM;                     // X rows (s)
    } else {
        A = Xh + (size_t)by * 128 * DM;
        B = Wh + (z == 0 ? (size_t)0 : (size_t)2 * DM * DM) + (size_t)bx * 128 * DM;
    }
    floatx4 acc[4][4] = {};
    gemm_bt_tile(A, B, DM, DM, DM, As, Bs, acc);

    const int lane = threadIdx.x & 63, wave = threadIdx.x >> 6;
    const int l15 = lane & 15, kq = lane >> 4;
    const int wm = (wave >> 1) * 64, wn = (wave & 1) * 64;
    if (z == 1) {
        const int b = by >> 4, st = by & 15;
        #pragma unroll
        for (int i = 0; i < 4; i++)
            #pragma unroll
            for (int j = 0; j < 4; j++)
                #pragma unroll
                for (int r = 0; r < 4; r++) {
                    int d = bx * 128 + wm + i * 16 + kq * 4 + r;
                    int s = st * 128 + wn + j * 16 + l15;
                    Vt[((size_t)b * DM + d) * SEQ + s] = (_Float16)(acc[i][j][r] + bv[d]);
                }
    } else {
        const float* bias = (z == 0) ? bk : bq;
        _Float16* outp    = (z == 0) ? Kh : Qh;
        #pragma unroll
        for (int i = 0; i < 4; i++)
            #pragma unroll
            for (int j = 0; j < 4; j++)
                #pragma unroll
                for (int r = 0; r < 4; r++) {
                    int row = by * 128 + wm + i * 16 + kq * 4 + r;
                    int col = bx * 128 + wn + j * 16 + l15;
                    outp[(size_t)row * DM + col] = (_Float16)(acc[i][j][r] + bias[col]);
                }
    }
}

// ---------------------------------------------------------------------------
// Kernel 3: scores (fp16) = Q.K^T * (1/32) + pad[b][k]; lower-triangle tiles
// (half)(-1e9 + s) == -inf, which exp()s to exactly 0 in the softmax.
// ---------------------------------------------------------------------------
__global__ __launch_bounds__(256) void scores_gemm(
    const _Float16* __restrict__ Qh, const _Float16* __restrict__ Kh,
    const float* __restrict__ pad, _Float16* __restrict__ Sc)
{
    const int bx = blockIdx.x, by = blockIdx.y, b = blockIdx.z;
    if (bx > by) return;  // causal
    __shared__ __align__(16) _Float16 As[128 * 32];
    __shared__ __align__(16) _Float16 Bs[128 * 32];
    const _Float16* A = Qh + ((size_t)b * SEQ + by * 128) * DM;
    const _Float16* B = Kh + ((size_t)b * SEQ + bx * 128) * DM;
    floatx4 acc[4][4] = {};
    gemm_bt_tile(A, B, DM, DM, DM, As, Bs, acc);

    const int lane = threadIdx.x & 63, wave = threadIdx.x >> 6;
    const int l15 = lane & 15, kq = lane >> 4;
    const int wm = (wave >> 1) * 64, wn = (wave & 1) * 64;
    #pragma unroll
    for (int i = 0; i < 4; i++)
        #pragma unroll
        for (int j = 0; j < 4; j++)
            #pragma unroll
            for (int r = 0; r < 4; r++) {
                int row = by * 128 + wm + i * 16 + kq * 4 + r;
                int col = bx * 128 + wn + j * 16 + l15;
                Sc[((size_t)b * SEQ + row) * SEQ + col] =
                    (_Float16)(acc[i][j][r] * 0.03125f + pad[b * SEQ + col]);
            }
}

// ---------------------------------------------------------------------------
// Kernel 4: in-place row softmax over k in [0,q]; zeros for k > q.
// One block per row; each thread owns 8 contiguous fp16 (one half8 load/store).
// ---------------------------------------------------------------------------
__global__ __launch_bounds__(256) void softmax_rows(_Float16* __restrict__ Sc)
{
    const int bid = blockIdx.x;
    const int b = bid >> 11, q = bid & (SEQ - 1);
    _Float16* row = Sc + ((size_t)b * SEQ + q) * SEQ;
    const int t = threadIdx.x;
    const int c0 = t * 8;
    __shared__ float red[4];

    half8 v = *(const half8*)(row + c0);
    float f[8];
    float m = -3.0e38f;
    #pragma unroll
    for (int e = 0; e < 8; e++) {
        f[e] = (c0 + e <= q) ? (float)v[e] : -3.0e38f;
        m = fmaxf(m, f[e]);
    }
    #pragma unroll
    for (int o = 32; o > 0; o >>= 1) m = fmaxf(m, __shfl_down(m, o));
    if ((t & 63) == 0) red[t >> 6] = m;
    __syncthreads();
    m = fmaxf(fmaxf(red[0], red[1]), fmaxf(red[2], red[3]));

    float ex[8], s = 0.f;
    #pragma unroll
    for (int e = 0; e < 8; e++) {
        ex[e] = (c0 + e <= q) ? __expf(f[e] - m) : 0.f;
        s += ex[e];
    }
    #pragma unroll
    for (int o = 32; o > 0; o >>= 1) s += __shfl_down(s, o);
    __syncthreads();
    if ((t & 63) == 0) red[t >> 6] = s;
    __syncthreads();
    s = red[0] + red[1] + red[2] + red[3];

    const float inv = 1.0f / s;
    half8 o8;
    #pragma unroll
    for (int e = 0; e < 8; e++) o8[e] = (_Float16)(ex[e] * inv);
    *(half8*)(row + c0) = o8;
}

// ---------------------------------------------------------------------------
// Kernel 5: O[q][d] = sum_k P[q][k] * Vt[d][k]; K-loop stops after q-tile
// ---------------------------------------------------------------------------
__global__ __launch_bounds__(256) void pv_gemm(
    const _Float16* __restrict__ P, const _Float16* __restrict__ Vt,
    float* __restrict__ out)
{
    __shared__ __align__(16) _Float16 As[128 * 32];
    __shared__ __align__(16) _Float16 Bs[128 * 32];
    const int bx = blockIdx.x, by = blockIdx.y, b = blockIdx.z;
    const _Float16* A = P  + ((size_t)b * SEQ + by * 128) * SEQ;
    const _Float16* B = Vt + ((size_t)b * DM  + bx * 128) * SEQ;
    const int kmax = (by + 1) * 128;  // P[q][k]=0 for k>q
    floatx4 acc[4][4] = {};
    gemm_bt_tile(A, B, SEQ, SEQ, kmax, As, Bs, acc);

    const int lane = threadIdx.x & 63, wave = threadIdx.x >> 6;
    const int l15 = lane & 15, kq = lane >> 4;
    const int wm = (wave >> 1) * 64, wn = (wave & 1) * 64;
    #pragma unroll
    for (int i = 0; i < 4; i++)
        #pragma unroll
        for (int j = 0; j < 4; j++)
            #pragma unroll
            for (int r = 0; r < 4; r++) {
                int row = by * 128 + wm + i * 16 + kq * 4 + r;
                int col = bx * 128 + wn + j * 16 + l15;
                out[((size_t)b * SEQ + row) * DM + col] = acc[i][j][r];
            }
}

// ---------------------------------------------------------------------------
// Workspace layout (bytes) — total 174,063,616 (was 308 MB in R1; suspected
// ws overflow -> GPU memory fault):
//   Wh @ 0         :  6,291,456  (3x1024x1024 fp16)
//   Qh @ 6291456   : 33,554,432
//   Kh @ 39845888  : 33,554,432
//   Vt @ 73400320  : 33,554,432  ([B][D][S] fp16, written directly by qkv z=1)
//   Sc @ 106954752 : 67,108,864  (8x2048x2048 fp16; softmax in-place -> P)
// Xh (fp16 src, 33.5 MB) lives in d_out; dead before pv_gemm writes out.
// ---------------------------------------------------------------------------
extern "C" void kernel_launch(void* const* d_in, const int* in_sizes, int n_in,
                              void* d_out, int out_size, void* d_ws, size_t ws_size,
                              hipStream_t stream) {
    const float* src = (const float*)d_in[0];
    const float* pad = (const float*)d_in[1];
    // d_in[2] = causal mask, handled analytically
    const float* Wk = (const float*)d_in[3];
    const float* bk = (const float*)d_in[4];
    const float* Wv = (const float*)d_in[5];
    const float* bv = (const float*)d_in[6];
    const float* Wq = (const float*)d_in[7];
    const float* bq = (const float*)d_in[8];
    float* out = (float*)d_out;

    char* ws = (char*)d_ws;
    _Float16* Wh = (_Float16*)(ws);
    _Float16* Qh = (_Float16*)(ws + 6291456);
    _Float16* Kh = (_Float16*)(ws + 39845888);
    _Float16* Vt = (_Float16*)(ws + 73400320);
    _Float16* Sc = (_Float16*)(ws + 106954752);
    _Float16* Xh = (_Float16*)d_out;  // scratch inside out buffer

    convert_inputs<<<2048, 256, 0, stream>>>(src, Wk, Wv, Wq, Xh, Wh);
    qkv_gemm<<<dim3(8, 128, 3), 256, 0, stream>>>(Xh, Wh, bk, bv, bq, Kh, Vt, Qh);
    scores_gemm<<<dim3(16, 16, BATCH), 256, 0, stream>>>(Qh, Kh, pad, Sc);
    softmax_rows<<<BATCH * SEQ, 256, 0, stream>>>(Sc);
    pv_gemm<<<dim3(8, 16, BATCH), 256, 0, stream>>>(Sc, Vt, out);
}

// Round 3
// 481.618 us; speedup vs baseline: 1.0498x; 1.0498x over previous
//
#include <hip/hip_runtime.h>
#include <cstdint>
#include <cstddef>

// Problem constants (B=8, S=2048, D=1024)
#define BATCH 8
#define SEQ   2048
#define DM    1024

typedef _Float16 half8 __attribute__((ext_vector_type(8)));
typedef float floatx4 __attribute__((ext_vector_type(4)));

#define GLOBAL_AS __attribute__((address_space(1)))
#define LDS_AS    __attribute__((address_space(3)))

// Async global->LDS, 16B per lane. LDS dest = wave-uniform base + lane*16.
__device__ __forceinline__ void gl_lds16(const _Float16* g, _Float16* l) {
    __builtin_amdgcn_global_load_lds((const GLOBAL_AS void*)g, (LDS_AS void*)l, 16, 0, 0);
}

// ---------------------------------------------------------------------------
// gemm_bt mainloop: C[m][n] = sum_k A[m][k] * B[n][k]
// Tile BM=BN=128, BK=32. Block = 256 threads = 4 waves in 2x2.
// ---------------------------------------------------------------------------
__device__ __forceinline__ void gemm_bt_tile(
    const _Float16* __restrict__ A, const _Float16* __restrict__ B,
    int lda, int ldb, int kmax,
    _Float16* As, _Float16* Bs, floatx4 (&acc)[4][4])
{
    const int t = threadIdx.x;
    const int wave = t >> 6, lane = t & 63;
    const int l15 = lane & 15, kq = lane >> 4;
    const int wm = (wave >> 1) * 64, wn = (wave & 1) * 64;
    const int sr = t >> 2;          // staging row 0..63
    const int sc = (t & 3) * 8;     // staging col (elements)
    _Float16* AsW = As + wave * 512;  // wave-uniform LDS base
    _Float16* BsW = Bs + wave * 512;

    for (int k0 = 0; k0 < kmax; k0 += 32) {
        __syncthreads();
        gl_lds16(A + (size_t)sr * lda + k0 + sc,        AsW);
        gl_lds16(A + (size_t)(sr + 64) * lda + k0 + sc, AsW + 2048);
        gl_lds16(B + (size_t)sr * ldb + k0 + sc,        BsW);
        gl_lds16(B + (size_t)(sr + 64) * ldb + k0 + sc, BsW + 2048);
        __syncthreads();

        half8 af[4], bfr[4];
        #pragma unroll
        for (int i = 0; i < 4; i++)
            af[i] = *(const half8*)&As[(wm + i * 16 + l15) * 32 + kq * 8];
        #pragma unroll
        for (int j = 0; j < 4; j++)
            bfr[j] = *(const half8*)&Bs[(wn + j * 16 + l15) * 32 + kq * 8];
        #pragma unroll
        for (int i = 0; i < 4; i++)
            #pragma unroll
            for (int j = 0; j < 4; j++)
                acc[i][j] = __builtin_amdgcn_mfma_f32_16x16x32_f16(af[i], bfr[j], acc[i][j], 0, 0, 0);
    }
}

// ---------------------------------------------------------------------------
// Kernel 1: fp32 -> fp16 (src -> Xh (lives in d_out), Wk/Wv/Wq -> Wh)
// ---------------------------------------------------------------------------
__global__ __launch_bounds__(256) void convert_inputs(
    const float* __restrict__ src,
    const float* __restrict__ Wk, const float* __restrict__ Wv, const float* __restrict__ Wq,
    _Float16* __restrict__ Xh, _Float16* __restrict__ Wh)
{
    const int64_t gid = (int64_t)blockIdx.x * 256 + threadIdx.x;
    const int64_t gs  = (int64_t)gridDim.x * 256;
    const int64_t nX = (int64_t)BATCH * SEQ * DM;
    const int64_t nW = (int64_t)DM * DM;
    for (int64_t i = gid; i < nX; i += gs) Xh[i] = (_Float16)src[i];
    for (int64_t i = gid; i < nW; i += gs) {
        Wh[i]          = (_Float16)Wk[i];
        Wh[nW + i]     = (_Float16)Wv[i];
        Wh[2 * nW + i] = (_Float16)Wq[i];
    }
}

// ---------------------------------------------------------------------------
// Kernel 2: QKV projection, 1D grid of 3072 with XCD-aware swizzle.
// Round-robin dispatch: XCD = L % 8. Each XCD owns by-range [16x, 16x+16),
// bx cycles fastest (W-tile cycle 2 MB stays L2-resident; A-tile 8-way reuse
// within one XCD), z outermost.
//   z=0: K[s][d]  = X·Wk^T + bk
//   z=1: Vt[d][s] = Wv·X^T + bv[row]
//   z=2: Q[s][d]  = X·Wq^T + bq
// ---------------------------------------------------------------------------
__global__ __launch_bounds__(256) void qkv_gemm(
    const _Float16* __restrict__ Xh, const _Float16* __restrict__ Wh,
    const float* __restrict__ bk, const float* __restrict__ bv, const float* __restrict__ bq,
    _Float16* __restrict__ Kh, _Float16* __restrict__ Vt, _Float16* __restrict__ Qh)
{
    __shared__ __align__(16) _Float16 As[128 * 32];
    __shared__ __align__(16) _Float16 Bs[128 * 32];
    const int L = blockIdx.x;
    const int x = L & 7, s = L >> 3;   // x = presumed XCD
    const int z = s >> 7;              // 0..2
    const int r = s & 127;
    const int by = x * 16 + (r >> 3);  // 0..127
    const int bx = r & 7;              // fastest

    const _Float16 *A, *B;
    if (z == 1) {
        A = Wh + (size_t)DM * DM + (size_t)bx * 128 * DM;   // Wv rows (d)
        B = Xh + (size_t)by * 128 * DM;                     // X rows (s)
    } else {
        A = Xh + (size_t)by * 128 * DM;
        B = Wh + (z == 0 ? (size_t)0 : (size_t)2 * DM * DM) + (size_t)bx * 128 * DM;
    }
    floatx4 acc[4][4] = {};
    gemm_bt_tile(A, B, DM, DM, DM, As, Bs, acc);

    const int lane = threadIdx.x & 63, wave = threadIdx.x >> 6;
    const int l15 = lane & 15, kq = lane >> 4;
    const int wm = (wave >> 1) * 64, wn = (wave & 1) * 64;
    if (z == 1) {
        const int b = by >> 4, st = by & 15;
        #pragma unroll
        for (int i = 0; i < 4; i++)
            #pragma unroll
            for (int j = 0; j < 4; j++)
                #pragma unroll
                for (int rr = 0; rr < 4; rr++) {
                    int d = bx * 128 + wm + i * 16 + kq * 4 + rr;
                    int sIdx = st * 128 + wn + j * 16 + l15;
                    Vt[((size_t)b * DM + d) * SEQ + sIdx] = (_Float16)(acc[i][j][rr] + bv[d]);
                }
    } else {
        const float* bias = (z == 0) ? bk : bq;
        _Float16* outp    = (z == 0) ? Kh : Qh;
        #pragma unroll
        for (int i = 0; i < 4; i++)
            #pragma unroll
            for (int j = 0; j < 4; j++)
                #pragma unroll
                for (int rr = 0; rr < 4; rr++) {
                    int row = by * 128 + wm + i * 16 + kq * 4 + rr;
                    int col = bx * 128 + wn + j * 16 + l15;
                    outp[(size_t)row * DM + col] = (_Float16)(acc[i][j][rr] + bias[col]);
                }
    }
}

// ---------------------------------------------------------------------------
// Kernel 3: scores (fp16) = Q.K^T * (1/32) + pad[b][k]; lower-triangle tiles
// (half)(-1e9 + s) == -inf, which exp()s to exactly 0 in the softmax.
// ---------------------------------------------------------------------------
__global__ __launch_bounds__(256) void scores_gemm(
    const _Float16* __restrict__ Qh, const _Float16* __restrict__ Kh,
    const float* __restrict__ pad, _Float16* __restrict__ Sc)
{
    const int bx = blockIdx.x, by = blockIdx.y, b = blockIdx.z;
    if (bx > by) return;  // causal
    __shared__ __align__(16) _Float16 As[128 * 32];
    __shared__ __align__(16) _Float16 Bs[128 * 32];
    const _Float16* A = Qh + ((size_t)b * SEQ + by * 128) * DM;
    const _Float16* B = Kh + ((size_t)b * SEQ + bx * 128) * DM;
    floatx4 acc[4][4] = {};
    gemm_bt_tile(A, B, DM, DM, DM, As, Bs, acc);

    const int lane = threadIdx.x & 63, wave = threadIdx.x >> 6;
    const int l15 = lane & 15, kq = lane >> 4;
    const int wm = (wave >> 1) * 64, wn = (wave & 1) * 64;
    #pragma unroll
    for (int i = 0; i < 4; i++)
        #pragma unroll
        for (int j = 0; j < 4; j++)
            #pragma unroll
            for (int r = 0; r < 4; r++) {
                int row = by * 128 + wm + i * 16 + kq * 4 + r;
                int col = bx * 128 + wn + j * 16 + l15;
                Sc[((size_t)b * SEQ + row) * SEQ + col] =
                    (_Float16)(acc[i][j][r] * 0.03125f + pad[b * SEQ + col]);
            }
}

// ---------------------------------------------------------------------------
// Kernel 4: in-place row softmax over k in [0,q]; zeros for k > q.
// One block per row; each thread owns 8 contiguous fp16 (one half8 load/store).
// ---------------------------------------------------------------------------
__global__ __launch_bounds__(256) void softmax_rows(_Float16* __restrict__ Sc)
{
    const int bid = blockIdx.x;
    const int b = bid >> 11, q = bid & (SEQ - 1);
    _Float16* row = Sc + ((size_t)b * SEQ + q) * SEQ;
    const int t = threadIdx.x;
    const int c0 = t * 8;
    __shared__ float red[4];

    half8 v = *(const half8*)(row + c0);
    float f[8];
    float m = -3.0e38f;
    #pragma unroll
    for (int e = 0; e < 8; e++) {
        f[e] = (c0 + e <= q) ? (float)v[e] : -3.0e38f;
        m = fmaxf(m, f[e]);
    }
    #pragma unroll
    for (int o = 32; o > 0; o >>= 1) m = fmaxf(m, __shfl_down(m, o));
    if ((t & 63) == 0) red[t >> 6] = m;
    __syncthreads();
    m = fmaxf(fmaxf(red[0], red[1]), fmaxf(red[2], red[3]));

    float ex[8], s = 0.f;
    #pragma unroll
    for (int e = 0; e < 8; e++) {
        ex[e] = (c0 + e <= q) ? __expf(f[e] - m) : 0.f;
        s += ex[e];
    }
    #pragma unroll
    for (int o = 32; o > 0; o >>= 1) s += __shfl_down(s, o);
    __syncthreads();
    if ((t & 63) == 0) red[t >> 6] = s;
    __syncthreads();
    s = red[0] + red[1] + red[2] + red[3];

    const float inv = 1.0f / s;
    half8 o8;
    #pragma unroll
    for (int e = 0; e < 8; e++) o8[e] = (_Float16)(ex[e] * inv);
    *(half8*)(row + c0) = o8;
}

// ---------------------------------------------------------------------------
// Kernel 5: O[q][d] = sum_k P[q][k] * Vt[d][k]; K-loop stops after q-tile.
// 1D grid of 1024 with XCD swizzle; by-pairs {x, 15-x} per XCD balance the
// triangular kmax across XCDs ((x+1)+(16-x) = 17 tiles, constant).
// ---------------------------------------------------------------------------
__global__ __launch_bounds__(256) void pv_gemm(
    const _Float16* __restrict__ P, const _Float16* __restrict__ Vt,
    float* __restrict__ out)
{
    __shared__ __align__(16) _Float16 As[128 * 32];
    __shared__ __align__(16) _Float16 Bs[128 * 32];
    const int L = blockIdx.x;
    const int x = L & 7, s = L >> 3;
    const int b = s >> 4;
    const int r = s & 15;
    const int by = (r < 8) ? x : 15 - x;
    const int bx = r & 7;

    const _Float16* A = P  + ((size_t)b * SEQ + by * 128) * SEQ;
    const _Float16* B = Vt + ((size_t)b * DM  + bx * 128) * SEQ;
    const int kmax = (by + 1) * 128;  // P[q][k]=0 for k>q
    floatx4 acc[4][4] = {};
    gemm_bt_tile(A, B, SEQ, SEQ, kmax, As, Bs, acc);

    const int lane = threadIdx.x & 63, wave = threadIdx.x >> 6;
    const int l15 = lane & 15, kq = lane >> 4;
    const int wm = (wave >> 1) * 64, wn = (wave & 1) * 64;
    #pragma unroll
    for (int i = 0; i < 4; i++)
        #pragma unroll
        for (int j = 0; j < 4; j++)
            #pragma unroll
            for (int rr = 0; rr < 4; rr++) {
                int row = by * 128 + wm + i * 16 + kq * 4 + rr;
                int col = bx * 128 + wn + j * 16 + l15;
                out[((size_t)b * SEQ + row) * DM + col] = acc[i][j][rr];
            }
}

// ---------------------------------------------------------------------------
// Workspace layout (bytes) — total 174,063,616:
//   Wh @ 0         :  6,291,456  (3x1024x1024 fp16)
//   Qh @ 6291456   : 33,554,432
//   Kh @ 39845888  : 33,554,432
//   Vt @ 73400320  : 33,554,432  ([B][D][S] fp16, written directly by qkv z=1)
//   Sc @ 106954752 : 67,108,864  (8x2048x2048 fp16; softmax in-place -> P)
// Xh (fp16 src, 33.5 MB) lives in d_out; dead before pv_gemm writes out.
// ---------------------------------------------------------------------------
extern "C" void kernel_launch(void* const* d_in, const int* in_sizes, int n_in,
                              void* d_out, int out_size, void* d_ws, size_t ws_size,
                              hipStream_t stream) {
    const float* src = (const float*)d_in[0];
    const float* pad = (const float*)d_in[1];
    // d_in[2] = causal mask, handled analytically
    const float* Wk = (const float*)d_in[3];
    const float* bk = (const float*)d_in[4];
    const float* Wv = (const float*)d_in[5];
    const float* bv = (const float*)d_in[6];
    const float* Wq = (const float*)d_in[7];
    const float* bq = (const float*)d_in[8];
    float* out = (float*)d_out;

    char* ws = (char*)d_ws;
    _Float16* Wh = (_Float16*)(ws);
    _Float16* Qh = (_Float16*)(ws + 6291456);
    _Float16* Kh = (_Float16*)(ws + 39845888);
    _Float16* Vt = (_Float16*)(ws + 73400320);
    _Float16* Sc = (_Float16*)(ws + 106954752);
    _Float16* Xh = (_Float16*)d_out;  // scratch inside out buffer

    convert_inputs<<<2048, 256, 0, stream>>>(src, Wk, Wv, Wq, Xh, Wh);
    qkv_gemm<<<3072, 256, 0, stream>>>(Xh, Wh, bk, bv, bq, Kh, Vt, Qh);
    scores_gemm<<<dim3(16, 16, BATCH), 256, 0, stream>>>(Qh, Kh, pad, Sc);
    softmax_rows<<<BATCH * SEQ, 256, 0, stream>>>(Sc);
    pv_gemm<<<1024, 256, 0, stream>>>(Sc, Vt, out);
}

// Round 4
// 459.566 us; speedup vs baseline: 1.1001x; 1.0480x over previous
//
#include <hip/hip_runtime.h>
#include <cstdint>
#include <cstddef>

// Problem constants (B=8, S=2048, D=1024)
#define BATCH 8
#define SEQ   2048
#define DM    1024

typedef _Float16 half8 __attribute__((ext_vector_type(8)));
typedef _Float16 half4v __attribute__((ext_vector_type(4)));
typedef float floatx4 __attribute__((ext_vector_type(4)));
typedef float float4v __attribute__((ext_vector_type(4)));

#define GLOBAL_AS __attribute__((address_space(1)))
#define LDS_AS    __attribute__((address_space(3)))

// Async global->LDS, 16B per lane. LDS dest = wave-uniform base + lane*16.
__device__ __forceinline__ void gl_lds16(const _Float16* g, _Float16* l) {
    __builtin_amdgcn_global_load_lds((const GLOBAL_AS void*)g, (LDS_AS void*)l, 16, 0, 0);
}

// ---------------------------------------------------------------------------
// gemm_bt mainloop: C[m][n] = sum_k A[m][k] * B[n][k]
// Tile BM=BN=128, BK=32. Block = 256 threads = 4 waves in 2x2.
// LDS bank-conflict fix: row stride is 64 B = 16 banks, so unswizzled
// fragment reads alias 4-way (R3 measured 1.26e7 conflict cycles/dispatch).
// XOR swizzle: 16B chunk stored at slot s holds global chunk s ^ ((row>>1)&3).
// Producer applies it to the *global* source column (LDS dest is fixed at
// lane*16); consumer inverts it on the ds_read address. Every 8-lane phase
// then covers all 32 banks exactly once (conflict-free).
// ---------------------------------------------------------------------------
__device__ __forceinline__ void gemm_bt_tile(
    const _Float16* __restrict__ A, const _Float16* __restrict__ B,
    int lda, int ldb, int kmax,
    _Float16* As, _Float16* Bs, floatx4 (&acc)[4][4])
{
    const int t = threadIdx.x;
    const int wave = t >> 6, lane = t & 63;
    const int l15 = lane & 15, kq = lane >> 4;
    const int wm = (wave >> 1) * 64, wn = (wave & 1) * 64;
    const int sr = t >> 2;                                  // staging row 0..63
    const int scc = ((t & 3) ^ ((sr >> 1) & 3)) * 8;        // swizzled src col
    const int slot = (kq ^ ((l15 >> 1) & 3)) * 8;           // consumer slot
    _Float16* AsW = As + wave * 512;  // wave-uniform LDS base
    _Float16* BsW = Bs + wave * 512;

    for (int k0 = 0; k0 < kmax; k0 += 32) {
        __syncthreads();
        gl_lds16(A + (size_t)sr * lda + k0 + scc,        AsW);
        gl_lds16(A + (size_t)(sr + 64) * lda + k0 + scc, AsW + 2048);
        gl_lds16(B + (size_t)sr * ldb + k0 + scc,        BsW);
        gl_lds16(B + (size_t)(sr + 64) * ldb + k0 + scc, BsW + 2048);
        __syncthreads();

        half8 af[4], bfr[4];
        #pragma unroll
        for (int i = 0; i < 4; i++)
            af[i] = *(const half8*)&As[(wm + i * 16 + l15) * 32 + slot];
        #pragma unroll
        for (int j = 0; j < 4; j++)
            bfr[j] = *(const half8*)&Bs[(wn + j * 16 + l15) * 32 + slot];
        #pragma unroll
        for (int i = 0; i < 4; i++)
            #pragma unroll
            for (int j = 0; j < 4; j++)
                acc[i][j] = __builtin_amdgcn_mfma_f32_16x16x32_f16(af[i], bfr[j], acc[i][j], 0, 0, 0);
    }
}

// ---------------------------------------------------------------------------
// Kernel 1: fp32 -> fp16, vectorized float4 -> half4 (was scalar).
// ---------------------------------------------------------------------------
__global__ __launch_bounds__(256) void convert_inputs(
    const float* __restrict__ src,
    const float* __restrict__ Wk, const float* __restrict__ Wv, const float* __restrict__ Wq,
    _Float16* __restrict__ Xh, _Float16* __restrict__ Wh)
{
    const int gid = blockIdx.x * 256 + threadIdx.x;
    const int gs  = gridDim.x * 256;
    const int nX4 = BATCH * SEQ * DM / 4;   // 4,194,304
    const int nW4 = DM * DM / 4;            // 262,144
    const float4v* s4  = (const float4v*)src;
    const float4v* wk4 = (const float4v*)Wk;
    const float4v* wv4 = (const float4v*)Wv;
    const float4v* wq4 = (const float4v*)Wq;
    half4v* x4 = (half4v*)Xh;
    half4v* w4 = (half4v*)Wh;
    for (int i = gid; i < nX4; i += gs) {
        float4v v = s4[i];
        half4v h;
        #pragma unroll
        for (int e = 0; e < 4; e++) h[e] = (_Float16)v[e];
        x4[i] = h;
    }
    for (int i = gid; i < nW4; i += gs) {
        float4v a = wk4[i], b = wv4[i], c = wq4[i];
        half4v ha, hb, hc;
        #pragma unroll
        for (int e = 0; e < 4; e++) { ha[e] = (_Float16)a[e]; hb[e] = (_Float16)b[e]; hc[e] = (_Float16)c[e]; }
        w4[i]           = ha;
        w4[nW4 + i]     = hb;
        w4[2 * nW4 + i] = hc;
    }
}

// ---------------------------------------------------------------------------
// Kernel 2: QKV projection, 1D grid 3072, XCD swizzle (XCD = L%8), z INNERMOST
// so each X-tile is fetched from HBM once and reused for all three GEMMs.
//   z=0: K[s][d]  = X·Wk^T + bk
//   z=1: Vt[d][s] = Wv·X^T + bv[row]
//   z=2: Q[s][d]  = X·Wq^T + bq
// ---------------------------------------------------------------------------
__global__ __launch_bounds__(256) void qkv_gemm(
    const _Float16* __restrict__ Xh, const _Float16* __restrict__ Wh,
    const float* __restrict__ bk, const float* __restrict__ bv, const float* __restrict__ bq,
    _Float16* __restrict__ Kh, _Float16* __restrict__ Vt, _Float16* __restrict__ Qh)
{
    __shared__ __align__(16) _Float16 As[128 * 32];
    __shared__ __align__(16) _Float16 Bs[128 * 32];
    const int L = blockIdx.x;
    const int x = L & 7, s = L >> 3;   // x = presumed XCD, s: 0..383
    const int z = s % 3;               // fastest: X-tile reused across z in L2
    const int u = s / 3;               // 0..127
    const int by = x * 16 + (u >> 3);  // 0..127
    const int bx = u & 7;

    const _Float16 *A, *B;
    if (z == 1) {
        A = Wh + (size_t)DM * DM + (size_t)bx * 128 * DM;   // Wv rows (d)
        B = Xh + (size_t)by * 128 * DM;                     // X rows (s)
    } else {
        A = Xh + (size_t)by * 128 * DM;
        B = Wh + (z == 0 ? (size_t)0 : (size_t)2 * DM * DM) + (size_t)bx * 128 * DM;
    }
    floatx4 acc[4][4] = {};
    gemm_bt_tile(A, B, DM, DM, DM, As, Bs, acc);

    const int lane = threadIdx.x & 63, wave = threadIdx.x >> 6;
    const int l15 = lane & 15, kq = lane >> 4;
    const int wm = (wave >> 1) * 64, wn = (wave & 1) * 64;
    if (z == 1) {
        const int b = by >> 4, st = by & 15;
        #pragma unroll
        for (int i = 0; i < 4; i++)
            #pragma unroll
            for (int j = 0; j < 4; j++)
                #pragma unroll
                for (int rr = 0; rr < 4; rr++) {
                    int d = bx * 128 + wm + i * 16 + kq * 4 + rr;
                    int sIdx = st * 128 + wn + j * 16 + l15;
                    Vt[((size_t)b * DM + d) * SEQ + sIdx] = (_Float16)(acc[i][j][rr] + bv[d]);
                }
    } else {
        const float* bias = (z == 0) ? bk : bq;
        _Float16* outp    = (z == 0) ? Kh : Qh;
        #pragma unroll
        for (int i = 0; i < 4; i++)
            #pragma unroll
            for (int j = 0; j < 4; j++)
                #pragma unroll
                for (int rr = 0; rr < 4; rr++) {
                    int row = by * 128 + wm + i * 16 + kq * 4 + rr;
                    int col = bx * 128 + wn + j * 16 + l15;
                    outp[(size_t)row * DM + col] = (_Float16)(acc[i][j][rr] + bias[col]);
                }
    }
}

// ---------------------------------------------------------------------------
// Kernel 3: scores (fp16) = Q.K^T * (1/32) + pad[b][k]; lower triangle only.
// Compact 1D grid of exactly the 1088 active tiles (was 2048 with 960 dead).
// XCD x owns by-pair {15-x, x} per batch (17 tiles, balanced; K/Q tiles stay
// XCD-local in L2). (half)(-1e9 + s) == -inf -> exp == 0 in softmax.
// ---------------------------------------------------------------------------
__global__ __launch_bounds__(256) void scores_gemm(
    const _Float16* __restrict__ Qh, const _Float16* __restrict__ Kh,
    const float* __restrict__ pad, _Float16* __restrict__ Sc)
{
    __shared__ __align__(16) _Float16 As[128 * 32];
    __shared__ __align__(16) _Float16 Bs[128 * 32];
    const int L = blockIdx.x;          // 0..1087
    const int x = L & 7, s = L >> 3;   // s: 0..135
    const int b = s / 17, w = s % 17;  // w: 0..16
    int by, bx;
    if (w < 16 - x) { by = 15 - x; bx = w; }
    else            { by = x;      bx = w - (16 - x); }

    const _Float16* A = Qh + ((size_t)b * SEQ + by * 128) * DM;
    const _Float16* B = Kh + ((size_t)b * SEQ + bx * 128) * DM;
    floatx4 acc[4][4] = {};
    gemm_bt_tile(A, B, DM, DM, DM, As, Bs, acc);

    const int lane = threadIdx.x & 63, wave = threadIdx.x >> 6;
    const int l15 = lane & 15, kq = lane >> 4;
    const int wm = (wave >> 1) * 64, wn = (wave & 1) * 64;
    #pragma unroll
    for (int i = 0; i < 4; i++)
        #pragma unroll
        for (int j = 0; j < 4; j++)
            #pragma unroll
            for (int r = 0; r < 4; r++) {
                int row = by * 128 + wm + i * 16 + kq * 4 + r;
                int col = bx * 128 + wn + j * 16 + l15;
                Sc[((size_t)b * SEQ + row) * SEQ + col] =
                    (_Float16)(acc[i][j][r] * 0.03125f + pad[b * SEQ + col]);
            }
}

// ---------------------------------------------------------------------------
// Kernel 4: in-place row softmax over k in [0,q]; zeros for k > q.
// ---------------------------------------------------------------------------
__global__ __launch_bounds__(256) void softmax_rows(_Float16* __restrict__ Sc)
{
    const int bid = blockIdx.x;
    const int b = bid >> 11, q = bid & (SEQ - 1);
    _Float16* row = Sc + ((size_t)b * SEQ + q) * SEQ;
    const int t = threadIdx.x;
    const int c0 = t * 8;
    __shared__ float red[4];

    half8 v = *(const half8*)(row + c0);
    float f[8];
    float m = -3.0e38f;
    #pragma unroll
    for (int e = 0; e < 8; e++) {
        f[e] = (c0 + e <= q) ? (float)v[e] : -3.0e38f;
        m = fmaxf(m, f[e]);
    }
    #pragma unroll
    for (int o = 32; o > 0; o >>= 1) m = fmaxf(m, __shfl_down(m, o));
    if ((t & 63) == 0) red[t >> 6] = m;
    __syncthreads();
    m = fmaxf(fmaxf(red[0], red[1]), fmaxf(red[2], red[3]));

    float ex[8], s = 0.f;
    #pragma unroll
    for (int e = 0; e < 8; e++) {
        ex[e] = (c0 + e <= q) ? __expf(f[e] - m) : 0.f;
        s += ex[e];
    }
    #pragma unroll
    for (int o = 32; o > 0; o >>= 1) s += __shfl_down(s, o);
    __syncthreads();
    if ((t & 63) == 0) red[t >> 6] = s;
    __syncthreads();
    s = red[0] + red[1] + red[2] + red[3];

    const float inv = 1.0f / s;
    half8 o8;
    #pragma unroll
    for (int e = 0; e < 8; e++) o8[e] = (_Float16)(ex[e] * inv);
    *(half8*)(row + c0) = o8;
}

// ---------------------------------------------------------------------------
// Kernel 5: O[q][d] = sum_k P[q][k] * Vt[d][k]; K-loop stops after q-tile.
// XCD pairing {15-x, x} AND longest-first: by=15 (64 K-iters, ~2x avg) now
// dispatches in the first 512 blocks instead of near-last (R3 straggler tail).
// ---------------------------------------------------------------------------
__global__ __launch_bounds__(256) void pv_gemm(
    const _Float16* __restrict__ P, const _Float16* __restrict__ Vt,
    float* __restrict__ out)
{
    __shared__ __align__(16) _Float16 As[128 * 32];
    __shared__ __align__(16) _Float16 Bs[128 * 32];
    const int L = blockIdx.x;
    const int x = L & 7, s = L >> 3;
    const int b = s >> 4;
    const int r = s & 15;
    const int by = (r < 8) ? (15 - x) : x;   // long tiles first
    const int bx = r & 7;

    const _Float16* A = P  + ((size_t)b * SEQ + by * 128) * SEQ;
    const _Float16* B = Vt + ((size_t)b * DM  + bx * 128) * SEQ;
    const int kmax = (by + 1) * 128;  // P[q][k]=0 for k>q
    floatx4 acc[4][4] = {};
    gemm_bt_tile(A, B, SEQ, SEQ, kmax, As, Bs, acc);

    const int lane = threadIdx.x & 63, wave = threadIdx.x >> 6;
    const int l15 = lane & 15, kq = lane >> 4;
    const int wm = (wave >> 1) * 64, wn = (wave & 1) * 64;
    #pragma unroll
    for (int i = 0; i < 4; i++)
        #pragma unroll
        for (int j = 0; j < 4; j++)
            #pragma unroll
            for (int rr = 0; rr < 4; rr++) {
                int row = by * 128 + wm + i * 16 + kq * 4 + rr;
                int col = bx * 128 + wn + j * 16 + l15;
                out[((size_t)b * SEQ + row) * DM + col] = acc[i][j][rr];
            }
}

// ---------------------------------------------------------------------------
// Workspace layout (bytes) — total 174,063,616:
//   Wh @ 0         :  6,291,456  (3x1024x1024 fp16)
//   Qh @ 6291456   : 33,554,432
//   Kh @ 39845888  : 33,554,432
//   Vt @ 73400320  : 33,554,432  ([B][D][S] fp16, written directly by qkv z=1)
//   Sc @ 106954752 : 67,108,864  (8x2048x2048 fp16; softmax in-place -> P)
// Xh (fp16 src, 33.5 MB) lives in d_out; dead before pv_gemm writes out.
// ---------------------------------------------------------------------------
extern "C" void kernel_launch(void* const* d_in, const int* in_sizes, int n_in,
                              void* d_out, int out_size, void* d_ws, size_t ws_size,
                              hipStream_t stream) {
    const float* src = (const float*)d_in[0];
    const float* pad = (const float*)d_in[1];
    // d_in[2] = causal mask, handled analytically
    const float* Wk = (const float*)d_in[3];
    const float* bk = (const float*)d_in[4];
    const float* Wv = (const float*)d_in[5];
    const float* bv = (const float*)d_in[6];
    const float* Wq = (const float*)d_in[7];
    const float* bq = (const float*)d_in[8];
    float* out = (float*)d_out;

    char* ws = (char*)d_ws;
    _Float16* Wh = (_Float16*)(ws);
    _Float16* Qh = (_Float16*)(ws + 6291456);
    _Float16* Kh = (_Float16*)(ws + 39845888);
    _Float16* Vt = (_Float16*)(ws + 73400320);
    _Float16* Sc = (_Float16*)(ws + 106954752);
    _Float16* Xh = (_Float16*)d_out;  // scratch inside out buffer

    convert_inputs<<<2048, 256, 0, stream>>>(src, Wk, Wv, Wq, Xh, Wh);
    qkv_gemm<<<3072, 256, 0, stream>>>(Xh, Wh, bk, bv, bq, Kh, Vt, Qh);
    scores_gemm<<<1088, 256, 0, stream>>>(Qh, Kh, pad, Sc);
    softmax_rows<<<BATCH * SEQ, 256, 0, stream>>>(Sc);
    pv_gemm<<<1024, 256, 0, stream>>>(Sc, Vt, out);
}

// Round 5
// 418.548 us; speedup vs baseline: 1.2079x; 1.0980x over previous
//
#include <hip/hip_runtime.h>
#include <cstdint>
#include <cstddef>

// Problem constants (B=8, S=2048, D=1024)
#define BATCH 8
#define SEQ   2048
#define DM    1024

typedef _Float16 half8 __attribute__((ext_vector_type(8)));
typedef _Float16 half4v __attribute__((ext_vector_type(4)));
typedef float floatx4 __attribute__((ext_vector_type(4)));
typedef float float4v __attribute__((ext_vector_type(4)));

#define GLOBAL_AS __attribute__((address_space(1)))
#define LDS_AS    __attribute__((address_space(3)))

// Async global->LDS, 16B per lane. LDS dest = wave-uniform base + lane*16.
__device__ __forceinline__ void gl_lds16(const _Float16* g, _Float16* l) {
    __builtin_amdgcn_global_load_lds((const GLOBAL_AS void*)g, (LDS_AS void*)l, 16, 0, 0);
}

// ---------------------------------------------------------------------------
// gemm_bt mainloop: C[m][n] = sum_k A[m][k] * B[n][k]
// Tile BM=BN=128, BK=64 (R5: was 32 — halves the per-iter vmcnt(0)+barrier
// drain, the m97-structure's known ~20% stall). LDS = 2x16 KB, still 3
// blocks/CU (VGPR-limited), no occupancy cliff (m132's BK=128 hit one).
// Swizzle: row = 128 B = 8 chunks of 16 B = exactly 32 banks, so unswizzled
// fragment reads would collide; store global chunk (j ^ (row&7)) at slot j.
// Consumer reads slot (chunk ^ (row&7)). Hand-checked: every wave64 b128
// read/write touches each bank exactly 8x = minimal (conflict-free).
// ---------------------------------------------------------------------------
__device__ __forceinline__ void gemm_bt_tile(
    const _Float16* __restrict__ A, const _Float16* __restrict__ B,
    int lda, int ldb, int kmax,
    _Float16* As, _Float16* Bs, floatx4 (&acc)[4][4])
{
    const int t = threadIdx.x;
    const int wave = t >> 6, lane = t & 63;
    const int l15 = lane & 15, kq = lane >> 4;
    const int wm = (wave >> 1) * 64, wn = (wave & 1) * 64;
    // staging: wave w issue i covers rows w*8 + i*32 + (lane>>3), chunk lane&7
    const int srow = wave * 8 + (lane >> 3);
    const int schunk = lane & 7;
    _Float16* AsW = As + wave * 512;   // + i*2048 elts per issue
    _Float16* BsW = Bs + wave * 512;
    const int cslot = ((kq ^ (l15 & 7)) * 8);          // k-half 0 consumer slot
    const int cslot1 = (((4 + kq) ^ (l15 & 7)) * 8);   // k-half 1

    for (int k0 = 0; k0 < kmax; k0 += 64) {
        __syncthreads();
        #pragma unroll
        for (int i = 0; i < 4; i++) {
            const int r = srow + i * 32;
            const int gcol = (schunk ^ (r & 7)) * 8;
            gl_lds16(A + (size_t)r * lda + k0 + gcol, AsW + i * 2048);
            gl_lds16(B + (size_t)r * ldb + k0 + gcol, BsW + i * 2048);
        }
        __syncthreads();

        {   // k-half 0
            half8 af[4], bfr[4];
            #pragma unroll
            for (int i = 0; i < 4; i++)
                af[i] = *(const half8*)&As[(wm + i * 16 + l15) * 64 + cslot];
            #pragma unroll
            for (int j = 0; j < 4; j++)
                bfr[j] = *(const half8*)&Bs[(wn + j * 16 + l15) * 64 + cslot];
            #pragma unroll
            for (int i = 0; i < 4; i++)
                #pragma unroll
                for (int j = 0; j < 4; j++)
                    acc[i][j] = __builtin_amdgcn_mfma_f32_16x16x32_f16(af[i], bfr[j], acc[i][j], 0, 0, 0);
        }
        {   // k-half 1
            half8 af[4], bfr[4];
            #pragma unroll
            for (int i = 0; i < 4; i++)
                af[i] = *(const half8*)&As[(wm + i * 16 + l15) * 64 + cslot1];
            #pragma unroll
            for (int j = 0; j < 4; j++)
                bfr[j] = *(const half8*)&Bs[(wn + j * 16 + l15) * 64 + cslot1];
            #pragma unroll
            for (int i = 0; i < 4; i++)
                #pragma unroll
                for (int j = 0; j < 4; j++)
                    acc[i][j] = __builtin_amdgcn_mfma_f32_16x16x32_f16(af[i], bfr[j], acc[i][j], 0, 0, 0);
        }
    }
}

// ---------------------------------------------------------------------------
// Kernel 1: fp32 -> fp16, vectorized float4 -> half4.
// ---------------------------------------------------------------------------
__global__ __launch_bounds__(256) void convert_inputs(
    const float* __restrict__ src,
    const float* __restrict__ Wk, const float* __restrict__ Wv, const float* __restrict__ Wq,
    _Float16* __restrict__ Xh, _Float16* __restrict__ Wh)
{
    const int gid = blockIdx.x * 256 + threadIdx.x;
    const int gs  = gridDim.x * 256;
    const int nX4 = BATCH * SEQ * DM / 4;
    const int nW4 = DM * DM / 4;
    const float4v* s4  = (const float4v*)src;
    const float4v* wk4 = (const float4v*)Wk;
    const float4v* wv4 = (const float4v*)Wv;
    const float4v* wq4 = (const float4v*)Wq;
    half4v* x4 = (half4v*)Xh;
    half4v* w4 = (half4v*)Wh;
    for (int i = gid; i < nX4; i += gs) {
        float4v v = s4[i];
        half4v h;
        #pragma unroll
        for (int e = 0; e < 4; e++) h[e] = (_Float16)v[e];
        x4[i] = h;
    }
    for (int i = gid; i < nW4; i += gs) {
        float4v a = wk4[i], b = wv4[i], c = wq4[i];
        half4v ha, hb, hc;
        #pragma unroll
        for (int e = 0; e < 4; e++) { ha[e] = (_Float16)a[e]; hb[e] = (_Float16)b[e]; hc[e] = (_Float16)c[e]; }
        w4[i]           = ha;
        w4[nW4 + i]     = hb;
        w4[2 * nW4 + i] = hc;
    }
}

// ---------------------------------------------------------------------------
// Kernel 2: QKV projection, 1D grid 3072, XCD swizzle (XCD = L%8).
// R5: reverted to R3 order (z outer, bx fastest) — R4's z-innermost thrashed
// the 4 MB per-XCD L2 (FETCH 98->168 MB, time-neutral but wasteful).
//   z=0: K[s][d]  = X·Wk^T + bk
//   z=1: Vt[d][s] = Wv·X^T + bv[row]
//   z=2: Q[s][d]  = X·Wq^T + bq
// ---------------------------------------------------------------------------
__global__ __launch_bounds__(256) void qkv_gemm(
    const _Float16* __restrict__ Xh, const _Float16* __restrict__ Wh,
    const float* __restrict__ bk, const float* __restrict__ bv, const float* __restrict__ bq,
    _Float16* __restrict__ Kh, _Float16* __restrict__ Vt, _Float16* __restrict__ Qh)
{
    __shared__ __align__(16) _Float16 As[128 * 64];
    __shared__ __align__(16) _Float16 Bs[128 * 64];
    const int L = blockIdx.x;
    const int x = L & 7, s = L >> 3;
    const int z = s >> 7;
    const int r = s & 127;
    const int by = x * 16 + (r >> 3);
    const int bx = r & 7;

    const _Float16 *A, *B;
    if (z == 1) {
        A = Wh + (size_t)DM * DM + (size_t)bx * 128 * DM;   // Wv rows (d)
        B = Xh + (size_t)by * 128 * DM;                     // X rows (s)
    } else {
        A = Xh + (size_t)by * 128 * DM;
        B = Wh + (z == 0 ? (size_t)0 : (size_t)2 * DM * DM) + (size_t)bx * 128 * DM;
    }
    floatx4 acc[4][4] = {};
    gemm_bt_tile(A, B, DM, DM, DM, As, Bs, acc);

    const int lane = threadIdx.x & 63, wave = threadIdx.x >> 6;
    const int l15 = lane & 15, kq = lane >> 4;
    const int wm = (wave >> 1) * 64, wn = (wave & 1) * 64;
    if (z == 1) {
        const int b = by >> 4, st = by & 15;
        #pragma unroll
        for (int i = 0; i < 4; i++)
            #pragma unroll
            for (int j = 0; j < 4; j++)
                #pragma unroll
                for (int rr = 0; rr < 4; rr++) {
                    int d = bx * 128 + wm + i * 16 + kq * 4 + rr;
                    int sIdx = st * 128 + wn + j * 16 + l15;
                    Vt[((size_t)b * DM + d) * SEQ + sIdx] = (_Float16)(acc[i][j][rr] + bv[d]);
                }
    } else {
        const float* bias = (z == 0) ? bk : bq;
        _Float16* outp    = (z == 0) ? Kh : Qh;
        #pragma unroll
        for (int i = 0; i < 4; i++)
            #pragma unroll
            for (int j = 0; j < 4; j++)
                #pragma unroll
                for (int rr = 0; rr < 4; rr++) {
                    int row = by * 128 + wm + i * 16 + kq * 4 + rr;
                    int col = bx * 128 + wn + j * 16 + l15;
                    outp[(size_t)row * DM + col] = (_Float16)(acc[i][j][rr] + bias[col]);
                }
    }
}

// ---------------------------------------------------------------------------
// Kernel 3: scores (fp16) = Q.K^T * (1/32) + pad[b][k]; lower triangle only.
// Compact 1D grid of the 1088 active tiles; XCD x owns by-pair {15-x, x}.
// (half)(-1e9 + s) == -inf -> exp == 0 in softmax.
// ---------------------------------------------------------------------------
__global__ __launch_bounds__(256) void scores_gemm(
    const _Float16* __restrict__ Qh, const _Float16* __restrict__ Kh,
    const float* __restrict__ pad, _Float16* __restrict__ Sc)
{
    __shared__ __align__(16) _Float16 As[128 * 64];
    __shared__ __align__(16) _Float16 Bs[128 * 64];
    const int L = blockIdx.x;          // 0..1087
    const int x = L & 7, s = L >> 3;   // s: 0..135
    const int b = s / 17, w = s % 17;  // w: 0..16
    int by, bx;
    if (w < 16 - x) { by = 15 - x; bx = w; }
    else            { by = x;      bx = w - (16 - x); }

    const _Float16* A = Qh + ((size_t)b * SEQ + by * 128) * DM;
    const _Float16* B = Kh + ((size_t)b * SEQ + bx * 128) * DM;
    floatx4 acc[4][4] = {};
    gemm_bt_tile(A, B, DM, DM, DM, As, Bs, acc);

    const int lane = threadIdx.x & 63, wave = threadIdx.x >> 6;
    const int l15 = lane & 15, kq = lane >> 4;
    const int wm = (wave >> 1) * 64, wn = (wave & 1) * 64;
    #pragma unroll
    for (int i = 0; i < 4; i++)
        #pragma unroll
        for (int j = 0; j < 4; j++)
            #pragma unroll
            for (int r = 0; r < 4; r++) {
                int row = by * 128 + wm + i * 16 + kq * 4 + r;
                int col = bx * 128 + wn + j * 16 + l15;
                Sc[((size_t)b * SEQ + row) * SEQ + col] =
                    (_Float16)(acc[i][j][r] * 0.03125f + pad[b * SEQ + col]);
            }
}

// ---------------------------------------------------------------------------
// Kernel 4: in-place row softmax over k in [0,q]; zeros for k in (q, kmaxr).
// R5: only touch cols < kmaxr = roundup(q+1,128) — the only region pv reads
// (halves softmax HBM traffic). All 256 threads still hit the barriers.
// ---------------------------------------------------------------------------
__global__ __launch_bounds__(256) void softmax_rows(_Float16* __restrict__ Sc)
{
    const int bid = blockIdx.x;
    const int b = bid >> 11, q = bid & (SEQ - 1);
    _Float16* row = Sc + ((size_t)b * SEQ + q) * SEQ;
    const int n = q + 1;
    const int kmaxr = ((q >> 7) + 1) << 7;
    const int t = threadIdx.x;
    const int c0 = t * 8;
    const bool active = (c0 < kmaxr);
    __shared__ float red[4];

    half8 v = {};
    if (active) v = *(const half8*)(row + c0);
    float f[8];
    float m = -3.0e38f;
    #pragma unroll
    for (int e = 0; e < 8; e++) {
        f[e] = (active && (c0 + e < n)) ? (float)v[e] : -3.0e38f;
        m = fmaxf(m, f[e]);
    }
    #pragma unroll
    for (int o = 32; o > 0; o >>= 1) m = fmaxf(m, __shfl_down(m, o));
    if ((t & 63) == 0) red[t >> 6] = m;
    __syncthreads();
    m = fmaxf(fmaxf(red[0], red[1]), fmaxf(red[2], red[3]));

    float ex[8], s = 0.f;
    #pragma unroll
    for (int e = 0; e < 8; e++) {
        ex[e] = (f[e] > -1.0e38f) ? __expf(f[e] - m) : 0.f;
        s += ex[e];
    }
    #pragma unroll
    for (int o = 32; o > 0; o >>= 1) s += __shfl_down(s, o);
    __syncthreads();
    if ((t & 63) == 0) red[t >> 6] = s;
    __syncthreads();
    s = red[0] + red[1] + red[2] + red[3];

    if (active) {
        const float inv = 1.0f / s;
        half8 o8;
        #pragma unroll
        for (int e = 0; e < 8; e++) o8[e] = (_Float16)(ex[e] * inv);
        *(half8*)(row + c0) = o8;
    }
}

// ---------------------------------------------------------------------------
// Kernel 5: O[q][d] = sum_k P[q][k] * Vt[d][k]; K-loop stops after q-tile.
// XCD pairing {15-x, x}, longest-first (straggler fix).
// ---------------------------------------------------------------------------
__global__ __launch_bounds__(256) void pv_gemm(
    const _Float16* __restrict__ P, const _Float16* __restrict__ Vt,
    float* __restrict__ out)
{
    __shared__ __align__(16) _Float16 As[128 * 64];
    __shared__ __align__(16) _Float16 Bs[128 * 64];
    const int L = blockIdx.x;
    const int x = L & 7, s = L >> 3;
    const int b = s >> 4;
    const int r = s & 15;
    const int by = (r < 8) ? (15 - x) : x;   // long tiles first
    const int bx = r & 7;

    const _Float16* A = P  + ((size_t)b * SEQ + by * 128) * SEQ;
    const _Float16* B = Vt + ((size_t)b * DM  + bx * 128) * SEQ;
    const int kmax = (by + 1) * 128;  // P[q][k]=0 for k>q
    floatx4 acc[4][4] = {};
    gemm_bt_tile(A, B, SEQ, SEQ, kmax, As, Bs, acc);

    const int lane = threadIdx.x & 63, wave = threadIdx.x >> 6;
    const int l15 = lane & 15, kq = lane >> 4;
    const int wm = (wave >> 1) * 64, wn = (wave & 1) * 64;
    #pragma unroll
    for (int i = 0; i < 4; i++)
        #pragma unroll
        for (int j = 0; j < 4; j++)
            #pragma unroll
            for (int rr = 0; rr < 4; rr++) {
                int row = by * 128 + wm + i * 16 + kq * 4 + rr;
                int col = bx * 128 + wn + j * 16 + l15;
                out[((size_t)b * SEQ + row) * DM + col] = acc[i][j][rr];
            }
}

// ---------------------------------------------------------------------------
// Workspace layout (bytes) — total 174,063,616:
//   Wh @ 0         :  6,291,456  (3x1024x1024 fp16)
//   Qh @ 6291456   : 33,554,432
//   Kh @ 39845888  : 33,554,432
//   Vt @ 73400320  : 33,554,432  ([B][D][S] fp16, written directly by qkv z=1)
//   Sc @ 106954752 : 67,108,864  (8x2048x2048 fp16; softmax in-place -> P)
// Xh (fp16 src, 33.5 MB) lives in d_out; dead before pv_gemm writes out.
// ---------------------------------------------------------------------------
extern "C" void kernel_launch(void* const* d_in, const int* in_sizes, int n_in,
                              void* d_out, int out_size, void* d_ws, size_t ws_size,
                              hipStream_t stream) {
    const float* src = (const float*)d_in[0];
    const float* pad = (const float*)d_in[1];
    // d_in[2] = causal mask, handled analytically
    const float* Wk = (const float*)d_in[3];
    const float* bk = (const float*)d_in[4];
    const float* Wv = (const float*)d_in[5];
    const float* bv = (const float*)d_in[6];
    const float* Wq = (const float*)d_in[7];
    const float* bq = (const float*)d_in[8];
    float* out = (float*)d_out;

    char* ws = (char*)d_ws;
    _Float16* Wh = (_Float16*)(ws);
    _Float16* Qh = (_Float16*)(ws + 6291456);
    _Float16* Kh = (_Float16*)(ws + 39845888);
    _Float16* Vt = (_Float16*)(ws + 73400320);
    _Float16* Sc = (_Float16*)(ws + 106954752);
    _Float16* Xh = (_Float16*)d_out;  // scratch inside out buffer

    convert_inputs<<<2048, 256, 0, stream>>>(src, Wk, Wv, Wq, Xh, Wh);
    qkv_gemm<<<3072, 256, 0, stream>>>(Xh, Wh, bk, bv, bq, Kh, Vt, Qh);
    scores_gemm<<<1088, 256, 0, stream>>>(Qh, Kh, pad, Sc);
    softmax_rows<<<BATCH * SEQ, 256, 0, stream>>>(Sc);
    pv_gemm<<<1024, 256, 0, stream>>>(Sc, Vt, out);
}